// Round 9
// baseline (353.662 us; speedup 1.0000x reference)
//
#include <hip/hip_runtime.h>

#define NN   100000
#define EMB  64
#define HID  128
#define OUTD 64
#define NE   1600000
#define NL   200000
#define NBUK 6250     // NN/16 buckets of exactly 16 nodes
#define NG   8        // per-XCD privatized copies
#define CAPG 88       // per-XCD bucket capacity; E=32, ~10 sigma margin
#define BSTR 6272     // padded per-group bcnt stride

__device__ __forceinline__ unsigned xcc_id() {
    unsigned v;
    asm volatile("s_getreg_b32 %0, hwreg(HW_REG_XCC_ID)" : "=s"(v));
    return v & (NG - 1);
}

// ---------------- bucket edges by dst>>4 into per-XCD private buckets ----------------
__global__ void bucket16_kernel(const int* __restrict__ src, const int* __restrict__ dst,
                                int* __restrict__ bcnt, int* __restrict__ tmp) {
    int i = blockIdx.x * blockDim.x + threadIdx.x;
    if (i >= NE) return;
    unsigned g = xcc_id();          // wave-uniform physical XCD id
    int d = dst[i];
    int s = src[i];
    int b = d >> 4;
    int pos = atomicAdd(&bcnt[g * BSTR + b], 1);
    if (pos < CAPG) tmp[(g * NBUK + b) * CAPG + pos] = ((d & 15) << 17) | s;
}

// ---------------- per-bucket aggregation via LDS micro-CSR + register gather -------
// L1=true : out[i] = (1/max(deg,1)) * sum_{j in N(i)} x[j]
// L1=false: out[i] = (1/max(deg,1)) * sum x[j] + hz[i] + bias   (fused z)
template<bool L1>
__global__ void __launch_bounds__(256) agg16_kernel(
        const int* __restrict__ bcnt, const int* __restrict__ tmp,
        const float* __restrict__ x,
        const float* __restrict__ hz, const float* __restrict__ bias,
        float* __restrict__ outp) {
    __shared__ int scnt[16];
    __shared__ int soff[16];
    __shared__ int scur[16];
    __shared__ int slist[NG * CAPG];   // <= 704 entries

    const int b    = blockIdx.x;
    const int tid  = threadIdx.x;
    const int lane = tid & 63;
    const int wv   = tid >> 6;         // 0..3

    if (tid < 16) scnt[tid] = 0;
    __syncthreads();

    // phase 1: per-node counts (= degree) over the 8 private lists
#pragma unroll
    for (int g = 0; g < NG; ++g) {
        const int cg = min(bcnt[g * BSTR + b], CAPG);
        const int* tb = tmp + (size_t)(g * NBUK + b) * CAPG;
        for (int i = tid; i < cg; i += 256)
            atomicAdd(&scnt[tb[i] >> 17], 1);
    }
    __syncthreads();

    // phase 2: exclusive scan of 16
    if (tid == 0) {
        int acc = 0;
        for (int r = 0; r < 16; ++r) {
            soff[r] = acc;
            scur[r] = acc;
            acc += scnt[r];
        }
    }
    __syncthreads();

    // phase 3: scatter src ids into per-node lists
#pragma unroll
    for (int g = 0; g < NG; ++g) {
        const int cg = min(bcnt[g * BSTR + b], CAPG);
        const int* tb = tmp + (size_t)(g * NBUK + b) * CAPG;
        for (int i = tid; i < cg; i += 256) {
            int p = tb[i];
            int pos = atomicAdd(&scur[p >> 17], 1);
            slist[pos] = p & 0x1FFFF;
        }
    }
    __syncthreads();

    // phase 4: per-node register gather; wave wv owns nodes wv, wv+4, wv+8, wv+12
    for (int r = wv; r < 16; r += 4) {
        const int node = b * 16 + r;
        const int s = soff[r];
        const int d = scnt[r];
        float acc = 0.f;
        int j = 0;
        for (; j + 8 <= d; j += 8) {
            int c0 = slist[s + j + 0], c1 = slist[s + j + 1];
            int c2 = slist[s + j + 2], c3 = slist[s + j + 3];
            int c4 = slist[s + j + 4], c5 = slist[s + j + 5];
            int c6 = slist[s + j + 6], c7 = slist[s + j + 7];
            float v0 = x[(size_t)c0 * 64 + lane];
            float v1 = x[(size_t)c1 * 64 + lane];
            float v2 = x[(size_t)c2 * 64 + lane];
            float v3 = x[(size_t)c3 * 64 + lane];
            float v4 = x[(size_t)c4 * 64 + lane];
            float v5 = x[(size_t)c5 * 64 + lane];
            float v6 = x[(size_t)c6 * 64 + lane];
            float v7 = x[(size_t)c7 * 64 + lane];
            acc += ((v0 + v1) + (v2 + v3)) + ((v4 + v5) + (v6 + v7));
        }
        if (j + 4 <= d) {
            int c0 = slist[s + j + 0], c1 = slist[s + j + 1];
            int c2 = slist[s + j + 2], c3 = slist[s + j + 3];
            float v0 = x[(size_t)c0 * 64 + lane];
            float v1 = x[(size_t)c1 * 64 + lane];
            float v2 = x[(size_t)c2 * 64 + lane];
            float v3 = x[(size_t)c3 * 64 + lane];
            acc += (v0 + v1) + (v2 + v3);
            j += 4;
        }
        for (; j < d; ++j) acc += x[(size_t)slist[s + j] * 64 + lane];

        const float inv = 1.0f / fmaxf((float)d, 1.0f);
        if (L1) {
            outp[(size_t)node * 64 + lane] = acc * inv;
        } else {
            outp[(size_t)node * 64 + lane] =
                acc * inv + hz[(size_t)node * 64 + lane] + bias[lane];
        }
    }
}

// ---------------- tiled GEMM: 128 nodes x 128 outs per block, K=128 blocked by 64 ----
// MODE 1 (layer 1): X = cat(agg, emb), W = cat_c(w1l, w1r), out = relu(XW^T + b1)
// MODE 2 (layer 2): X = h, W rows: o<64 w2l[o], o>=64 w2r[o-64]; outs->outA(p2)/outB(hz)
template<int MODE>
__global__ void __launch_bounds__(512, 1) gemm_kernel(
        const float* __restrict__ Xa, const float* __restrict__ Xb,
        const float* __restrict__ Wa, const float* __restrict__ Wb,
        const float* __restrict__ bias,
        float* __restrict__ outA, float* __restrict__ outB) {
    __shared__ float lds_x[64 * 128];  // [c_local][node_local]
    __shared__ float lds_w[64 * 128];  // [c_local][o]

    const int tid = threadIdx.x;
    const int n_base = blockIdx.x * 128;

    const int ng = tid & 31;   // nodes 4*ng .. 4*ng+3
    const int og = tid >> 5;   // outs  8*og .. 8*og+7
    const int o0 = og * 8;

    float acc[4][8];
#pragma unroll
    for (int i = 0; i < 4; ++i)
#pragma unroll
        for (int j = 0; j < 8; ++j) acc[i][j] = 0.f;

#pragma unroll
    for (int half = 0; half < 2; ++half) {
        // ---- stage W half (transposed): lds_w[c][o] ----
        {
            int o = tid >> 2;
            int wslot = tid & 3;
#pragma unroll
            for (int k = 0; k < 4; ++k) {
                int s = wslot + 4 * k;   // float4 slot 0..15 within 64 c's
                int c4 = s * 4;          // local c
                float4 v;
                if (MODE == 1) {
                    v = (half == 0) ? ((const float4*)Wa)[o * 16 + s]
                                    : ((const float4*)Wb)[o * 16 + s];
                } else {
                    int cg4 = half * 16 + s;
                    v = (o < 64) ? ((const float4*)Wa)[o * 32 + cg4]
                                 : ((const float4*)Wb)[(o - 64) * 32 + cg4];
                }
                lds_w[(c4 + 0) * 128 + o] = v.x;
                lds_w[(c4 + 1) * 128 + o] = v.y;
                lds_w[(c4 + 2) * 128 + o] = v.z;
                lds_w[(c4 + 3) * 128 + o] = v.w;
            }
        }
        // ---- stage X half (transposed): lds_x[c][n_local] ----
        {
            int nl = tid >> 2;
            int cslot = tid & 3;
            int n = n_base + nl;
            bool ok = n < NN;
#pragma unroll
            for (int k = 0; k < 4; ++k) {
                int s = cslot + 4 * k;   // 0..15
                int c4 = s * 4;
                float4 v = make_float4(0.f, 0.f, 0.f, 0.f);
                if (ok) {
                    if (MODE == 1) {
                        v = (half == 0) ? ((const float4*)Xa)[(size_t)n * 16 + s]
                                        : ((const float4*)Xb)[(size_t)n * 16 + s];
                    } else {
                        v = ((const float4*)Xa)[(size_t)n * 32 + half * 16 + s];
                    }
                }
                lds_x[(c4 + 0) * 128 + nl] = v.x;
                lds_x[(c4 + 1) * 128 + nl] = v.y;
                lds_x[(c4 + 2) * 128 + nl] = v.z;
                lds_x[(c4 + 3) * 128 + nl] = v.w;
            }
        }
        __syncthreads();

        // ---- compute half ----
#pragma unroll 2
        for (int c = 0; c < 64; ++c) {
            float4 xv = *(const float4*)&lds_x[c * 128 + ng * 4];
            float4 w0 = *(const float4*)&lds_w[c * 128 + o0];
            float4 w1 = *(const float4*)&lds_w[c * 128 + o0 + 4];
            float xr[4] = {xv.x, xv.y, xv.z, xv.w};
            float wr[8] = {w0.x, w0.y, w0.z, w0.w, w1.x, w1.y, w1.z, w1.w};
#pragma unroll
            for (int i = 0; i < 4; ++i)
#pragma unroll
                for (int j = 0; j < 8; ++j) acc[i][j] += xr[i] * wr[j];
        }
        __syncthreads();
    }

    // ---- epilogue ----
    if (MODE == 1) {
        float bj[8];
#pragma unroll
        for (int j = 0; j < 8; ++j) bj[j] = bias[o0 + j];
#pragma unroll
        for (int i = 0; i < 4; ++i) {
            int n = n_base + ng * 4 + i;
            if (n >= NN) continue;
            float4 lo = make_float4(fmaxf(acc[i][0] + bj[0], 0.f), fmaxf(acc[i][1] + bj[1], 0.f),
                                    fmaxf(acc[i][2] + bj[2], 0.f), fmaxf(acc[i][3] + bj[3], 0.f));
            float4 hi = make_float4(fmaxf(acc[i][4] + bj[4], 0.f), fmaxf(acc[i][5] + bj[5], 0.f),
                                    fmaxf(acc[i][6] + bj[6], 0.f), fmaxf(acc[i][7] + bj[7], 0.f));
            ((float4*)outA)[(size_t)n * 32 + (o0 >> 2)] = lo;
            ((float4*)outA)[(size_t)n * 32 + (o0 >> 2) + 1] = hi;
        }
    } else {
        float* dstp = (og < 8) ? outA : outB;
        int ob = (og < 8) ? o0 : (o0 - 64);
#pragma unroll
        for (int i = 0; i < 4; ++i) {
            int n = n_base + ng * 4 + i;
            if (n >= NN) continue;
            float4 lo = make_float4(acc[i][0], acc[i][1], acc[i][2], acc[i][3]);
            float4 hi = make_float4(acc[i][4], acc[i][5], acc[i][6], acc[i][7]);
            ((float4*)dstp)[(size_t)n * 16 + (ob >> 2)] = lo;
            ((float4*)dstp)[(size_t)n * 16 + (ob >> 2) + 1] = hi;
        }
    }
}

// ---------------- decode: out[k] = dot(z[a[k]], z[b[k]]) ----------------
__global__ void decode_kernel(const int* __restrict__ a, const int* __restrict__ b,
                              const float* __restrict__ z, float* __restrict__ out) {
    int t = blockIdx.x * blockDim.x + threadIdx.x;
    int k = t >> 4;
    int q = t & 15;
    if (k >= NL) return;
    int ia = a[k], ib = b[k];
    float4 va = ((const float4*)z)[ia * 16 + q];
    float4 vb = ((const float4*)z)[ib * 16 + q];
    float s = va.x * vb.x + va.y * vb.y + va.z * vb.z + va.w * vb.w;
    s += __shfl_xor(s, 1, 64);
    s += __shfl_xor(s, 2, 64);
    s += __shfl_xor(s, 4, 64);
    s += __shfl_xor(s, 8, 64);
    if (q == 0) out[k] = s;
}

extern "C" void kernel_launch(void* const* d_in, const int* in_sizes, int n_in,
                              void* d_out, int out_size, void* d_ws, size_t ws_size,
                              hipStream_t stream) {
    const float* emb = (const float*)d_in[0];
    const float* w1l = (const float*)d_in[1];
    const float* w1r = (const float*)d_in[2];
    const float* b1  = (const float*)d_in[3];
    const float* w2l = (const float*)d_in[4];
    const float* w2r = (const float*)d_in[5];
    const float* b2  = (const float*)d_in[6];
    const int*   ei  = (const int*)d_in[7];
    const int*   eli = (const int*)d_in[8];
    float* out = (float*)d_out;

    // workspace layout (~120 MB)
    int* bcnt    = (int*)d_ws;                        // NG*BSTR = 50,176
    int* tmp     = bcnt + NG * BSTR;                  // NG*NBUK*CAPG = 4,400,000
    float* agg   = (float*)(tmp + (size_t)NG * NBUK * CAPG);  // NN*64 (reused as hz)
    float* h     = agg + (size_t)NN * 64;             // NN*128 (reused as z)
    float* p2    = h + (size_t)NN * 128;              // NN*64
    float* hz    = agg;
    float* z     = h;

    const int* src = ei;
    const int* dst = ei + NE;

    hipMemsetAsync(bcnt, 0, (size_t)NG * BSTR * sizeof(int), stream);

    // bucket edges by dst>>4 into per-XCD private lists (local-L2 atomics + write combining)
    bucket16_kernel<<<(NE + 255) / 256, 256, 0, stream>>>(src, dst, bcnt, tmp);

    const int NT = (NN + 127) / 128;  // 782 tiles

    // layer 1: agg = mean-gather(emb); h = relu(cat(agg,emb) @ cat(w1l,w1r)^T + b1)
    agg16_kernel<true><<<NBUK, 256, 0, stream>>>(bcnt, tmp, emb, nullptr, nullptr, agg);
    gemm_kernel<1><<<NT, 512, 0, stream>>>(agg, emb, w1l, w1r, b1, h, nullptr);

    // layer 2: {p2, hz} = h @ {w2l, w2r}^T ; z = mean-gather(p2) + hz + b2
    gemm_kernel<2><<<NT, 512, 0, stream>>>(h, nullptr, w2l, w2r, nullptr, p2, hz);
    agg16_kernel<false><<<NBUK, 256, 0, stream>>>(bcnt, tmp, p2, hz, b2, z);

    // decode
    decode_kernel<<<(NL * 16 + 255) / 256, 256, 0, stream>>>(eli, eli + NL, z, out);
}

// Round 10
// 337.079 us; speedup vs baseline: 1.0492x; 1.0492x over previous
//
#include <hip/hip_runtime.h>

#define NN   100000
#define EMB  64
#define HID  128
#define OUTD 64
#define NE   1600000
#define NL   200000
#define NBUK 6250     // NN/16 buckets of exactly 16 nodes
#define NG   8        // per-XCD privatized copies
#define CAPG 88       // per-XCD bucket capacity; E=32, ~10 sigma margin
#define BSTR 6272     // padded per-group bcnt stride

__device__ __forceinline__ unsigned xcc_id() {
    unsigned v;
    asm volatile("s_getreg_b32 %0, hwreg(HW_REG_XCC_ID)" : "=s"(v));
    return v & (NG - 1);
}

// ---------------- bucket edges by dst>>4 into per-XCD private buckets ----------------
__global__ void bucket16_kernel(const int* __restrict__ src, const int* __restrict__ dst,
                                int* __restrict__ bcnt, int* __restrict__ tmp) {
    int i = blockIdx.x * blockDim.x + threadIdx.x;
    if (i >= NE) return;
    unsigned g = xcc_id();          // wave-uniform physical XCD id
    int d = dst[i];
    int s = src[i];
    int b = d >> 4;
    int pos = atomicAdd(&bcnt[g * BSTR + b], 1);
    if (pos < CAPG) tmp[(g * NBUK + b) * CAPG + pos] = ((d & 15) << 17) | s;
}

// ---------------- per-bucket aggregation via LDS micro-CSR + register gather -------
// L1=true : out[i] = (1/max(deg,1)) * sum_{j in N(i)} x[j]
// L1=false: out[i] = (1/max(deg,1)) * sum x[j] + hz[i] + bias   (fused z)
template<bool L1>
__global__ void __launch_bounds__(256) agg16_kernel(
        const int* __restrict__ bcnt, const int* __restrict__ tmp,
        const float* __restrict__ x,
        const float* __restrict__ hz, const float* __restrict__ bias,
        float* __restrict__ outp) {
    __shared__ int scnt[16];
    __shared__ int soff[16];
    __shared__ int scur[16];
    __shared__ int slist[NG * CAPG];   // <= 704 entries

    const int b    = blockIdx.x;
    const int tid  = threadIdx.x;
    const int lane = tid & 63;
    const int wv   = tid >> 6;         // 0..3

    if (tid < 16) scnt[tid] = 0;
    __syncthreads();

    // phase 1: per-node counts (= degree) over the 8 private lists
#pragma unroll
    for (int g = 0; g < NG; ++g) {
        const int cg = min(bcnt[g * BSTR + b], CAPG);
        const int* tb = tmp + (size_t)(g * NBUK + b) * CAPG;
        for (int i = tid; i < cg; i += 256)
            atomicAdd(&scnt[tb[i] >> 17], 1);
    }
    __syncthreads();

    // phase 2: exclusive scan of 16
    if (tid == 0) {
        int acc = 0;
        for (int r = 0; r < 16; ++r) {
            soff[r] = acc;
            scur[r] = acc;
            acc += scnt[r];
        }
    }
    __syncthreads();

    // phase 3: scatter src ids into per-node lists
#pragma unroll
    for (int g = 0; g < NG; ++g) {
        const int cg = min(bcnt[g * BSTR + b], CAPG);
        const int* tb = tmp + (size_t)(g * NBUK + b) * CAPG;
        for (int i = tid; i < cg; i += 256) {
            int p = tb[i];
            int pos = atomicAdd(&scur[p >> 17], 1);
            slist[pos] = p & 0x1FFFF;
        }
    }
    __syncthreads();

    // phase 4: per-node register gather; wave wv owns nodes wv, wv+4, wv+8, wv+12
    for (int r = wv; r < 16; r += 4) {
        const int node = b * 16 + r;
        const int s = soff[r];
        const int d = scnt[r];
        float acc = 0.f;
        int j = 0;
        for (; j + 8 <= d; j += 8) {
            int c0 = slist[s + j + 0], c1 = slist[s + j + 1];
            int c2 = slist[s + j + 2], c3 = slist[s + j + 3];
            int c4 = slist[s + j + 4], c5 = slist[s + j + 5];
            int c6 = slist[s + j + 6], c7 = slist[s + j + 7];
            float v0 = x[(size_t)c0 * 64 + lane];
            float v1 = x[(size_t)c1 * 64 + lane];
            float v2 = x[(size_t)c2 * 64 + lane];
            float v3 = x[(size_t)c3 * 64 + lane];
            float v4 = x[(size_t)c4 * 64 + lane];
            float v5 = x[(size_t)c5 * 64 + lane];
            float v6 = x[(size_t)c6 * 64 + lane];
            float v7 = x[(size_t)c7 * 64 + lane];
            acc += ((v0 + v1) + (v2 + v3)) + ((v4 + v5) + (v6 + v7));
        }
        if (j + 4 <= d) {
            int c0 = slist[s + j + 0], c1 = slist[s + j + 1];
            int c2 = slist[s + j + 2], c3 = slist[s + j + 3];
            float v0 = x[(size_t)c0 * 64 + lane];
            float v1 = x[(size_t)c1 * 64 + lane];
            float v2 = x[(size_t)c2 * 64 + lane];
            float v3 = x[(size_t)c3 * 64 + lane];
            acc += (v0 + v1) + (v2 + v3);
            j += 4;
        }
        for (; j < d; ++j) acc += x[(size_t)slist[s + j] * 64 + lane];

        const float inv = 1.0f / fmaxf((float)d, 1.0f);
        if (L1) {
            outp[(size_t)node * 64 + lane] = acc * inv;
        } else {
            outp[(size_t)node * 64 + lane] =
                acc * inv + hz[(size_t)node * 64 + lane] + bias[lane];
        }
    }
}

// ---------------- fused 2-layer GEMM: 128 nodes x 128 outs per block ----------------
// GEMM1: h = relu(cat(agg,emb) @ cat_c(w1l,w1r)^T + b1)   (h kept in LDS only)
// GEMM2: p2 = h @ w2l^T (outs 0..63), hz = h @ w2r^T (outs 64..127)
__global__ void __launch_bounds__(512) gemm_fused_kernel(
        const float* __restrict__ agg, const float* __restrict__ emb,
        const float* __restrict__ w1l, const float* __restrict__ w1r,
        const float* __restrict__ b1,
        const float* __restrict__ w2l, const float* __restrict__ w2r,
        float* __restrict__ p2, float* __restrict__ hz) {
    __shared__ float lds_x[64 * 128];  // [c_local][node_local]; reused as hbuf in GEMM2
    __shared__ float lds_w[64 * 128];  // [c_local][o]

    const int tid = threadIdx.x;
    const int n_base = blockIdx.x * 128;

    const int ng = tid & 31;   // nodes 4*ng .. 4*ng+3
    const int og = tid >> 5;   // outs  8*og .. 8*og+7
    const int o0 = og * 8;

    float acc1[4][8];
#pragma unroll
    for (int i = 0; i < 4; ++i)
#pragma unroll
        for (int j = 0; j < 8; ++j) acc1[i][j] = 0.f;

    // ================= GEMM 1 =================
#pragma unroll
    for (int half = 0; half < 2; ++half) {
        // stage W1 half (transposed): lds_w[c][o]; row o = cat(w1l[o], w1r[o])
        {
            int o = tid >> 2;
            int wslot = tid & 3;
#pragma unroll
            for (int k = 0; k < 4; ++k) {
                int s = wslot + 4 * k;   // float4 slot 0..15
                int c4 = s * 4;
                float4 v = (half == 0) ? ((const float4*)w1l)[o * 16 + s]
                                       : ((const float4*)w1r)[o * 16 + s];
                lds_w[(c4 + 0) * 128 + o] = v.x;
                lds_w[(c4 + 1) * 128 + o] = v.y;
                lds_w[(c4 + 2) * 128 + o] = v.z;
                lds_w[(c4 + 3) * 128 + o] = v.w;
            }
        }
        // stage X half (transposed): lds_x[c][n]; X = cat(agg, emb)
        {
            int nl = tid >> 2;
            int cslot = tid & 3;
            int n = n_base + nl;
            bool ok = n < NN;
#pragma unroll
            for (int k = 0; k < 4; ++k) {
                int s = cslot + 4 * k;   // 0..15
                int c4 = s * 4;
                float4 v = make_float4(0.f, 0.f, 0.f, 0.f);
                if (ok) {
                    v = (half == 0) ? ((const float4*)agg)[(size_t)n * 16 + s]
                                    : ((const float4*)emb)[(size_t)n * 16 + s];
                }
                lds_x[(c4 + 0) * 128 + nl] = v.x;
                lds_x[(c4 + 1) * 128 + nl] = v.y;
                lds_x[(c4 + 2) * 128 + nl] = v.z;
                lds_x[(c4 + 3) * 128 + nl] = v.w;
            }
        }
        __syncthreads();

#pragma unroll 2
        for (int c = 0; c < 64; ++c) {
            float4 xv = *(const float4*)&lds_x[c * 128 + ng * 4];
            float4 w0 = *(const float4*)&lds_w[c * 128 + o0];
            float4 w1 = *(const float4*)&lds_w[c * 128 + o0 + 4];
            float xr[4] = {xv.x, xv.y, xv.z, xv.w};
            float wr[8] = {w0.x, w0.y, w0.z, w0.w, w1.x, w1.y, w1.z, w1.w};
#pragma unroll
            for (int i = 0; i < 4; ++i)
#pragma unroll
                for (int j = 0; j < 8; ++j) acc1[i][j] += xr[i] * wr[j];
        }
        __syncthreads();
    }

    // bias for this thread's h channels
    float b1v[8];
#pragma unroll
    for (int j = 0; j < 8; ++j) b1v[j] = b1[o0 + j];

    float acc2[4][8];
#pragma unroll
    for (int i = 0; i < 4; ++i)
#pragma unroll
        for (int j = 0; j < 8; ++j) acc2[i][j] = 0.f;

    // ================= GEMM 2 (h lives in lds_x) =================
#pragma unroll
    for (int kh = 0; kh < 2; ++kh) {
        // write h channels [kh*64, kh*64+64) into hbuf (= lds_x), transposed [c][n]
        if ((og >> 3) == kh) {
            int cb = o0 - kh * 64;   // 0..56
#pragma unroll
            for (int j = 0; j < 8; ++j) {
                float4 hv = make_float4(
                    fmaxf(acc1[0][j] + b1v[j], 0.f),
                    fmaxf(acc1[1][j] + b1v[j], 0.f),
                    fmaxf(acc1[2][j] + b1v[j], 0.f),
                    fmaxf(acc1[3][j] + b1v[j], 0.f));
                *(float4*)&lds_x[(cb + j) * 128 + ng * 4] = hv;
            }
        }
        // stage W2 half kh: row o: o<64 -> w2l[o], o>=64 -> w2r[o-64]
        {
            int o = tid >> 2;
            int wslot = tid & 3;
#pragma unroll
            for (int k = 0; k < 4; ++k) {
                int s = wslot + 4 * k;   // 0..15
                int cg4 = kh * 16 + s;   // global c float4 slot
                float4 v = (o < 64) ? ((const float4*)w2l)[o * 32 + cg4]
                                    : ((const float4*)w2r)[(o - 64) * 32 + cg4];
                int c4 = s * 4;
                lds_w[(c4 + 0) * 128 + o] = v.x;
                lds_w[(c4 + 1) * 128 + o] = v.y;
                lds_w[(c4 + 2) * 128 + o] = v.z;
                lds_w[(c4 + 3) * 128 + o] = v.w;
            }
        }
        __syncthreads();

#pragma unroll 2
        for (int c = 0; c < 64; ++c) {
            float4 xv = *(const float4*)&lds_x[c * 128 + ng * 4];
            float4 w0 = *(const float4*)&lds_w[c * 128 + o0];
            float4 w1 = *(const float4*)&lds_w[c * 128 + o0 + 4];
            float xr[4] = {xv.x, xv.y, xv.z, xv.w};
            float wr[8] = {w0.x, w0.y, w0.z, w0.w, w1.x, w1.y, w1.z, w1.w};
#pragma unroll
            for (int i = 0; i < 4; ++i)
#pragma unroll
                for (int j = 0; j < 8; ++j) acc2[i][j] += xr[i] * wr[j];
        }
        __syncthreads();
    }

    // epilogue: og<8 -> p2, og>=8 -> hz
    {
        float* dstp = (og < 8) ? p2 : hz;
        int ob = (og < 8) ? o0 : (o0 - 64);
#pragma unroll
        for (int i = 0; i < 4; ++i) {
            int n = n_base + ng * 4 + i;
            if (n >= NN) continue;
            float4 lo = make_float4(acc2[i][0], acc2[i][1], acc2[i][2], acc2[i][3]);
            float4 hi = make_float4(acc2[i][4], acc2[i][5], acc2[i][6], acc2[i][7]);
            ((float4*)dstp)[(size_t)n * 16 + (ob >> 2)] = lo;
            ((float4*)dstp)[(size_t)n * 16 + (ob >> 2) + 1] = hi;
        }
    }
}

// ---------------- decode: out[k] = dot(z[a[k]], z[b[k]]) ----------------
__global__ void decode_kernel(const int* __restrict__ a, const int* __restrict__ b,
                              const float* __restrict__ z, float* __restrict__ out) {
    int t = blockIdx.x * blockDim.x + threadIdx.x;
    int k = t >> 4;
    int q = t & 15;
    if (k >= NL) return;
    int ia = a[k], ib = b[k];
    float4 va = ((const float4*)z)[ia * 16 + q];
    float4 vb = ((const float4*)z)[ib * 16 + q];
    float s = va.x * vb.x + va.y * vb.y + va.z * vb.z + va.w * vb.w;
    s += __shfl_xor(s, 1, 64);
    s += __shfl_xor(s, 2, 64);
    s += __shfl_xor(s, 4, 64);
    s += __shfl_xor(s, 8, 64);
    if (q == 0) out[k] = s;
}

extern "C" void kernel_launch(void* const* d_in, const int* in_sizes, int n_in,
                              void* d_out, int out_size, void* d_ws, size_t ws_size,
                              hipStream_t stream) {
    const float* emb = (const float*)d_in[0];
    const float* w1l = (const float*)d_in[1];
    const float* w1r = (const float*)d_in[2];
    const float* b1  = (const float*)d_in[3];
    const float* w2l = (const float*)d_in[4];
    const float* w2r = (const float*)d_in[5];
    const float* b2  = (const float*)d_in[6];
    const int*   ei  = (const int*)d_in[7];
    const int*   eli = (const int*)d_in[8];
    float* out = (float*)d_out;

    // workspace layout (~95 MB)
    int* bcnt    = (int*)d_ws;                                // NG*BSTR = 50,176
    int* tmp     = bcnt + NG * BSTR;                          // NG*NBUK*CAPG = 4,400,000
    float* agg   = (float*)(tmp + (size_t)NG * NBUK * CAPG);  // NN*64 (reused as z)
    float* p2    = agg + (size_t)NN * 64;                     // NN*64
    float* hz    = p2 + (size_t)NN * 64;                      // NN*64
    float* z     = agg;   // agg fully consumed by gemm_fused before z is written

    const int* src = ei;
    const int* dst = ei + NE;

    hipMemsetAsync(bcnt, 0, (size_t)NG * BSTR * sizeof(int), stream);

    // bucket edges by dst>>4 into per-XCD private lists
    bucket16_kernel<<<(NE + 255) / 256, 256, 0, stream>>>(src, dst, bcnt, tmp);

    const int NT = (NN + 127) / 128;  // 782 tiles

    // layer 1 aggregation: agg = mean-gather(emb)
    agg16_kernel<true><<<NBUK, 256, 0, stream>>>(bcnt, tmp, emb, nullptr, nullptr, agg);

    // fused layers: h = relu(cat(agg,emb)@cat(w1l,w1r)^T + b1); {p2,hz} = h@{w2l,w2r}^T
    gemm_fused_kernel<<<NT, 512, 0, stream>>>(agg, emb, w1l, w1r, b1, w2l, w2r, p2, hz);

    // layer 2 aggregation + fuse: z = mean-gather(p2) + hz + b2
    agg16_kernel<false><<<NBUK, 256, 0, stream>>>(bcnt, tmp, p2, hz, b2, z);

    // decode
    decode_kernel<<<(NL * 16 + 255) / 256, 256, 0, stream>>>(eli, eli + NL, z, out);
}